// Round 10
// baseline (163.242 us; speedup 1.0000x reference)
//
#include <hip/hip_runtime.h>
#include <hip/hip_bf16.h>
#include <math.h>

#define Bq 4
#define Hh 16
#define Lq 1024
#define Dd 64
#define Kk 8
#define QT 128        // q rows per block (32 per wave, 4 waves)
#define KT 128        // k rows per iteration = 2 sub-tiles of 64
#define SRk 72        // K LDS row stride (bf16 elems)
#define SRv 136       // V^T LDS row stride (128 cols + pad)
#define TB 1152       // bias table entries per copy (4 shifted copies)
#define FMAX 8.0f     // fixed softmax shift (verified safe R1-R8)
#define LOG2E 1.44269504f

typedef __attribute__((ext_vector_type(8))) short short8;   // 8 bf16
typedef __attribute__((ext_vector_type(16))) float f32x16;

union frag_u {                    // build MFMA frags from packed uints
    short8 s;
    unsigned int u[4];
};

// packed f32x2 -> bf16x2 (RNE). On gfx950 lowers to v_cvt_pk_bf16_f32:
// 1 VALU instr per pair vs ~4-5 for scalar round+shift+pack (R5 post-mortem:
// conversions were the largest VALU consumer at VALUBusy=38%).
__device__ __forceinline__ unsigned int pk2(float a, float b) {
    __hip_bfloat162 h = __float22bfloat162_rn(float2{a, b});
    return *reinterpret_cast<unsigned int*>(&h);
}

// j-permutation (verified R4-R8): V row j -> column slot so the S^T C/D
// register layout IS the PV A-fragment layout (P never touches LDS).
__device__ __forceinline__ int jperm(int j) {
    return (j & 32) | ((j & 8) << 1) | ((j & 4) << 1) | ((j & 16) >> 2) | (j & 3);
}

// ---------------------------------------------------------------------------
// Single fused kernel (R5 structure — best measured attn config, 49 us).
// Block = 256 (4 waves), grid = (64 bh, 8 q-tiles).
// mfma_f32_32x32x16_bf16.  Wave w owns q rows 32w..32w+31.
//   S^T = K Q^T:  A = K rows (m=j), B = Q (k=d, n=i=l31).
//   C/D layout: col=lane&31 (=i), row=(r&3)+8*(r>>2)+4*(lane>>5) (=j_loc).
//   O = P V:      A = P from registers (jperm trick), B = V^T tile.
// Fixed-max softmax: p = exp2(S + (bias-FMAX)*log2e), Q pre-scaled 0.125*log2e.
// __launch_bounds__(256,2): 128-VGPR cap, spill-free (R6/R7 post-mortem:
// (256,4) capped at 64 VGPRs and spilled ~700 MB scratch traffic).
// ---------------------------------------------------------------------------
__global__ __launch_bounds__(256, 2) void attn_kernel(
    const float* __restrict__ qp, const float* __restrict__ kp,
    const float* __restrict__ vp,
    const float* __restrict__ off, const float* __restrict__ amp,
    const float* __restrict__ sh, const float* __restrict__ bpar,
    float* __restrict__ out)
{
    __shared__ __align__(16) short k_s[KT * SRk];   // 18432 B  K rows [j][d]
    __shared__ __align__(16) short v_s[Dd * SRv];   // 17408 B  V^T [d][slot^swz]
    __shared__ __align__(16) float bias4[4 * TB];   // 18432 B  4 shifted copies
    __shared__ float l_s[QT];                       //   512 B

    const int bh = blockIdx.x;            // fastest -> XCD = bh%8
    const int qs = blockIdx.y * QT;
    const int t  = threadIdx.x;
    const int w  = t >> 6;
    const int lane = t & 63;
    const int l31 = lane & 31;
    const int h5  = lane >> 5;
    const int h   = bh & 15;

    // ---- bias copy 0: (log(ksum+eps+bp) - |rel|*slope - FMAX)*log2e ----
    float slope = (h < Hh - 2) ? 4.605170185988092f * exp2f(-6.0f * (float)h / 13.0f) : 0.0f;
    #pragma unroll
    for (int it = 0; it < 5; ++it) {
        int i = it * 256 + t;
        if (i < TB - 1) {
            float rel = (float)(i - 127 - qs);
            float ksum = 0.0f;
            #pragma unroll
            for (int kk = 0; kk < Kk; ++kk) {
                float a = amp[kk * Hh + h];
                float o = off[kk * Hh + h];
                float s = sh[kk * Hh + h];
                float sgn = (a > 0.0f) ? 1.0f : ((a < 0.0f) ? -1.0f : 0.0f);
                ksum += fabsf(a) / (1.0f + __expf(-sgn * (rel - o) / s));
            }
            bias4[i] = (logf(ksum + 1e-8f + bpar[h]) - fabsf(rel) * slope - FMAX) * LOG2E;
        }
    }

    // ---- Q B-frags (global, once), scale folded, packed converts ----
    const float QS = 0.125f * LOG2E;
    short8 bq[4];
    const float* qrow = qp + ((size_t)bh * Lq + qs + 32 * w + l31) * Dd;
    #pragma unroll
    for (int c = 0; c < 4; ++c) {
        float4 x0 = *(const float4*)(qrow + c * 16 + h5 * 8);
        float4 x1 = *(const float4*)(qrow + c * 16 + h5 * 8 + 4);
        frag_u a;
        a.u[0] = pk2(x0.x * QS, x0.y * QS);
        a.u[1] = pk2(x0.z * QS, x0.w * QS);
        a.u[2] = pk2(x1.x * QS, x1.y * QS);
        a.u[3] = pk2(x1.z * QS, x1.w * QS);
        bq[c] = a.s;
    }

    // ---- staging geometry: thread owns 4 consecutive rows x 4 cols per sub
    const int g  = t >> 4;
    const int cl = t & 15;
    const int j0 = 4 * g;
    const int c4 = 4 * cl;
    const int vcb[2] = { jperm(j0), 64 + jperm(j0) };
    const float* kbase = kp + (size_t)bh * Lq * Dd;
    const float* vbase = vp + (size_t)bh * Lq * Dd;

    // ---- prefetch iteration 0 (kept as float4 regs so loads stay in flight)
    float4 kr[2][4], vr[2][4];
    #pragma unroll
    for (int s = 0; s < 2; ++s)
        #pragma unroll
        for (int u = 0; u < 4; ++u) {
            kr[s][u] = *(const float4*)(kbase + (size_t)(64 * s + j0 + u) * Dd + c4);
            vr[s][u] = *(const float4*)(vbase + (size_t)(64 * s + j0 + u) * Dd + c4);
        }

    __syncthreads();                      // bias copy0 visible

    // ---- replicate bias copies 1..3 (copyP[i] = bias(i+P)) ----
    #pragma unroll
    for (int it = 0; it < 5; ++it) {
        int i = it * 256 + t;
        if (i < TB) {
            float b1 = bias4[i + 1 <= TB - 2 ? i + 1 : TB - 2];
            float b2 = bias4[i + 2 <= TB - 2 ? i + 2 : TB - 2];
            float b3 = bias4[i + 3 <= TB - 2 ? i + 3 : TB - 2];
            bias4[TB + i]     = b1;
            bias4[2 * TB + i] = b2;
            bias4[3 * TB + i] = b3;
        }
    }
    // ---- write tile 0: K row-major b64; V reg-transposed 4x4 -> b64 ----
    #pragma unroll
    for (int s = 0; s < 2; ++s) {
        #pragma unroll
        for (int u = 0; u < 4; ++u) {
            uint2 kv;
            kv.x = pk2(kr[s][u].x, kr[s][u].y);
            kv.y = pk2(kr[s][u].z, kr[s][u].w);
            *(uint2*)&k_s[(64 * s + j0 + u) * SRk + c4] = kv;
        }
        #pragma unroll
        for (int cc = 0; cc < 4; ++cc) {
            int d = c4 + cc;
            uint2 vv;
            vv.x = pk2(((const float*)&vr[s][0])[cc], ((const float*)&vr[s][1])[cc]);
            vv.y = pk2(((const float*)&vr[s][2])[cc], ((const float*)&vr[s][3])[cc]);
            *(uint2*)&v_s[d * SRv + (vcb[s] ^ (8 * ((d >> 3) & 7)))] = vv;
        }
    }
    __syncthreads();

    // ---- accumulators ----
    f32x16 O0, O1;
    #pragma unroll
    for (int r = 0; r < 16; ++r) { O0[r] = 0.f; O1[r] = 0.f; }
    float l_part = 0.0f;

    const int L0 = 4 * h5 - 32 * w - l31 + 127;   // bias lane offset
    const int phi = L0 & 3;
    const float* bcopy = bias4 + phi * TB - phi;  // aligned-float4 view

    #pragma unroll 1
    for (int kt = 0; kt < Lq / KT; ++kt) {        // 8 iterations
        const int ks = kt * KT;

        // prefetch next iteration (VMEM overlaps compute below)
        if (kt < 7) {
            const float* kn = kbase + (size_t)(ks + KT) * Dd;
            const float* vn = vbase + (size_t)(ks + KT) * Dd;
            #pragma unroll
            for (int s = 0; s < 2; ++s)
                #pragma unroll
                for (int u = 0; u < 4; ++u) {
                    kr[s][u] = *(const float4*)(kn + (size_t)(64 * s + j0 + u) * Dd + c4);
                    vr[s][u] = *(const float4*)(vn + (size_t)(64 * s + j0 + u) * Dd + c4);
                }
        }

        #pragma unroll
        for (int s = 0; s < 2; ++s) {
            // ---- S^T = K Q^T (sub-tile s) ----
            f32x16 S0, S1;
            #pragma unroll
            for (int r = 0; r < 16; ++r) { S0[r] = 0.f; S1[r] = 0.f; }
            #pragma unroll
            for (int c = 0; c < 4; ++c) {
                short8 ak0 = *(const short8*)&k_s[(64 * s + l31) * SRk + c * 16 + h5 * 8];
                S0 = __builtin_amdgcn_mfma_f32_32x32x16_bf16(ak0, bq[c], S0, 0, 0, 0);
            }
            #pragma unroll
            for (int c = 0; c < 4; ++c) {
                short8 ak1 = *(const short8*)&k_s[(64 * s + 32 + l31) * SRk + c * 16 + h5 * 8];
                S1 = __builtin_amdgcn_mfma_f32_32x32x16_bf16(ak1, bq[c], S1, 0, 0, 0);
            }

            // ---- softmax: p = exp2(S + bias') ----
            float lsum = 0.0f;
            #pragma unroll
            for (int p = 0; p < 4; ++p) {
                int base0 = ks + 64 * s + 8 * p + L0;
                float4 b0 = *(const float4*)(bcopy + base0);
                float4 b1 = *(const float4*)(bcopy + base0 + 32);
                #pragma unroll
                for (int q = 0; q < 4; ++q) {
                    int r = 4 * p + q;
                    float bq0 = (q == 0) ? b0.x : (q == 1) ? b0.y : (q == 2) ? b0.z : b0.w;
                    float bq1 = (q == 0) ? b1.x : (q == 1) ? b1.y : (q == 2) ? b1.z : b1.w;
                    float e0 = __builtin_amdgcn_exp2f(S0[r] + bq0);
                    float e1 = __builtin_amdgcn_exp2f(S1[r] + bq1);
                    S0[r] = e0; S1[r] = e1;
                    lsum += e0 + e1;
                }
            }
            l_part += lsum;

            // ---- P A-frags in-register (jperm trick) with packed converts:
            // pair elements (e,e+1) map to consecutive S regs -> one pk2 each
            short8 ap[4];
            #pragma unroll
            for (int c = 0; c < 4; ++c) {
                int b = (c & 1) * 4;
                frag_u a;
                if (c >> 1) {
                    a.u[0] = pk2(S1[b + 0], S1[b + 1]);
                    a.u[1] = pk2(S1[b + 2], S1[b + 3]);
                    a.u[2] = pk2(S1[b + 8], S1[b + 9]);
                    a.u[3] = pk2(S1[b + 10], S1[b + 11]);
                } else {
                    a.u[0] = pk2(S0[b + 0], S0[b + 1]);
                    a.u[1] = pk2(S0[b + 2], S0[b + 3]);
                    a.u[2] = pk2(S0[b + 8], S0[b + 9]);
                    a.u[3] = pk2(S0[b + 10], S0[b + 11]);
                }
                ap[c] = a.s;
            }

            // ---- O += P V (sub-tile s) ----
            #pragma unroll
            for (int nb = 0; nb < 2; ++nb) {
                int d = nb * 32 + l31;
                int swz = 8 * ((d >> 3) & 7);
                f32x16 acc = nb ? O1 : O0;
                #pragma unroll
                for (int c = 0; c < 4; ++c) {
                    short8 bv = *(const short8*)&v_s[d * SRv + 64 * s + ((c * 16 + h5 * 8) ^ swz)];
                    acc = __builtin_amdgcn_mfma_f32_32x32x16_bf16(ap[c], bv, acc, 0, 0, 0);
                }
                if (nb) O1 = acc; else O0 = acc;
            }
        }

        __syncthreads();                  // all waves done reading k_s/v_s
        if (kt < 7) {
            #pragma unroll
            for (int s = 0; s < 2; ++s) {
                #pragma unroll
                for (int u = 0; u < 4; ++u) {
                    uint2 kv;
                    kv.x = pk2(kr[s][u].x, kr[s][u].y);
                    kv.y = pk2(kr[s][u].z, kr[s][u].w);
                    *(uint2*)&k_s[(64 * s + j0 + u) * SRk + c4] = kv;
                }
                #pragma unroll
                for (int cc = 0; cc < 4; ++cc) {
                    int d = c4 + cc;
                    uint2 vv;
                    vv.x = pk2(((const float*)&vr[s][0])[cc], ((const float*)&vr[s][1])[cc]);
                    vv.y = pk2(((const float*)&vr[s][2])[cc], ((const float*)&vr[s][3])[cc]);
                    *(uint2*)&v_s[d * SRv + (vcb[s] ^ (8 * ((d >> 3) & 7)))] = vv;
                }
            }
        }
        __syncthreads();
    }

    // ---- epilogue: finish row sums (i = l31), normalize, store ----
    float l = l_part;
    l += __shfl_xor(l, 32);               // other j-half
    l_s[32 * w + l31] = 1.0f / l;
    float* ob = out + ((size_t)bh * Lq + qs) * Dd;
    #pragma unroll
    for (int r = 0; r < 16; ++r) {
        int rowp = (r & 3) + 8 * (r >> 2) + 4 * h5;
        float inv = l_s[32 * w + rowp];   // same-wave write, wave-ordered
        ob[(size_t)(32 * w + rowp) * Dd + l31]      = O0[r] * inv;
        ob[(size_t)(32 * w + rowp) * Dd + 32 + l31] = O1[r] * inv;
    }
}

extern "C" void kernel_launch(void* const* d_in, const int* in_sizes, int n_in,
                              void* d_out, int out_size, void* d_ws, size_t ws_size,
                              hipStream_t stream) {
    const float* q   = (const float*)d_in[0];
    const float* k   = (const float*)d_in[1];
    const float* v   = (const float*)d_in[2];
    const float* off = (const float*)d_in[3];
    const float* amp = (const float*)d_in[4];
    const float* sh  = (const float*)d_in[5];
    const float* bp  = (const float*)d_in[6];
    float* out = (float*)d_out;

    dim3 grid(Bq * Hh, Lq / QT);          // (64, 8), bh fastest -> XCD locality
    attn_kernel<<<grid, 256, 0, stream>>>(q, k, v, off, amp, sh, bp, out);
}

// Round 11
// 124.277 us; speedup vs baseline: 1.3135x; 1.3135x over previous
//
#include <hip/hip_runtime.h>
#include <math.h>

#define Bq 4
#define Hh 16
#define Lq 1024
#define Dd 64
#define Kk 8
#define QT 128        // q rows per block (32 per wave, 4 waves)
#define KT 128        // k rows per iteration = 2 sub-tiles of 64
#define SRk 72        // K LDS row stride (bf16 elems)
#define SRv 136       // V^T LDS row stride (128 cols + pad)
#define TB 1152       // bias table entries per copy (4 shifted copies)
#define FMAX 8.0f     // fixed softmax shift (verified safe R1-R9)
#define LOG2E 1.44269504f

typedef __attribute__((ext_vector_type(8))) short short8;         // 8 bf16
typedef __attribute__((ext_vector_type(4))) unsigned int u32x4;   // 4 dwords
typedef __attribute__((ext_vector_type(16))) float f32x16;

// packed f32x2 -> bf16x2, round-half-up — BIT-IDENTICAL to R5's f2bh
// ((u+0x8000)>>16) but 3 VALU ops/pair via v_perm_b32 byte select.
// R9 post-mortem: __float22bfloat162_rn + reinterpret_cast took a local's
// address -> un-promoted alloca -> ~110 MB scratch traffic. Pure int ops only.
__device__ __forceinline__ unsigned int pk2(float a, float b) {
    return __builtin_amdgcn_perm(__float_as_uint(b) + 0x8000u,
                                 __float_as_uint(a) + 0x8000u,
                                 0x07060302u);
}

// j-permutation (verified R4-R9): V row j -> column slot so the S^T C/D
// register layout IS the PV A-fragment layout (P never touches LDS).
__device__ __forceinline__ int jperm(int j) {
    return (j & 32) | ((j & 8) << 1) | ((j & 4) << 1) | ((j & 16) >> 2) | (j & 3);
}

// ---------------------------------------------------------------------------
// Single fused kernel (R5 structure — best measured config: 49 us attn).
// Block = 256 (4 waves), grid = (64 bh, 8 q-tiles).
// mfma_f32_32x32x16_bf16.  Wave w owns q rows 32w..32w+31.
//   S^T = K Q^T:  A = K rows (m=j), B = Q (k=d, n=i=l31).
//   C/D layout: col=lane&31 (=i), row=(r&3)+8*(r>>2)+4*(lane>>5) (=j_loc).
//   O = P V:      A = P from registers (jperm trick), B = V^T tile.
// Fixed-max softmax: p = exp2(S + (bias-FMAX)*log2e), Q pre-scaled 0.125*log2e.
// __launch_bounds__(256,2): 128-VGPR cap, spill-free (R6/R7: (256,4) capped
// VGPRs at 64 and spilled ~700 MB of scratch traffic per launch).
// ---------------------------------------------------------------------------
__global__ __launch_bounds__(256, 2) void attn_kernel(
    const float* __restrict__ qp, const float* __restrict__ kp,
    const float* __restrict__ vp,
    const float* __restrict__ off, const float* __restrict__ amp,
    const float* __restrict__ sh, const float* __restrict__ bpar,
    float* __restrict__ out)
{
    __shared__ __align__(16) short k_s[KT * SRk];   // 18432 B  K rows [j][d]
    __shared__ __align__(16) short v_s[Dd * SRv];   // 17408 B  V^T [d][slot^swz]
    __shared__ __align__(16) float bias4[4 * TB];   // 18432 B  4 shifted copies
    __shared__ float l_s[QT];                       //   512 B

    const int bh = blockIdx.x;            // fastest -> XCD = bh%8
    const int qs = blockIdx.y * QT;
    const int t  = threadIdx.x;
    const int w  = t >> 6;
    const int lane = t & 63;
    const int l31 = lane & 31;
    const int h5  = lane >> 5;
    const int h   = bh & 15;

    // ---- bias copy 0: (log(ksum+eps+bp) - |rel|*slope - FMAX)*log2e ----
    float slope = (h < Hh - 2) ? 4.605170185988092f * exp2f(-6.0f * (float)h / 13.0f) : 0.0f;
    #pragma unroll
    for (int it = 0; it < 5; ++it) {
        int i = it * 256 + t;
        if (i < TB - 1) {
            float rel = (float)(i - 127 - qs);
            float ksum = 0.0f;
            #pragma unroll
            for (int kk = 0; kk < Kk; ++kk) {
                float a = amp[kk * Hh + h];
                float o = off[kk * Hh + h];
                float s = sh[kk * Hh + h];
                float sgn = (a > 0.0f) ? 1.0f : ((a < 0.0f) ? -1.0f : 0.0f);
                ksum += fabsf(a) / (1.0f + __expf(-sgn * (rel - o) / s));
            }
            bias4[i] = (logf(ksum + 1e-8f + bpar[h]) - fabsf(rel) * slope - FMAX) * LOG2E;
        }
    }

    // ---- Q B-frags (global, once), scale folded, packed converts ----
    const float QS = 0.125f * LOG2E;
    short8 bq[4];
    const float* qrow = qp + ((size_t)bh * Lq + qs + 32 * w + l31) * Dd;
    #pragma unroll
    for (int c = 0; c < 4; ++c) {
        float4 x0 = *(const float4*)(qrow + c * 16 + h5 * 8);
        float4 x1 = *(const float4*)(qrow + c * 16 + h5 * 8 + 4);
        u32x4 a;
        a[0] = pk2(x0.x * QS, x0.y * QS);
        a[1] = pk2(x0.z * QS, x0.w * QS);
        a[2] = pk2(x1.x * QS, x1.y * QS);
        a[3] = pk2(x1.z * QS, x1.w * QS);
        bq[c] = __builtin_bit_cast(short8, a);
    }

    // ---- staging geometry: thread owns 4 consecutive rows x 4 cols per sub
    const int g  = t >> 4;
    const int cl = t & 15;
    const int j0 = 4 * g;
    const int c4 = 4 * cl;
    const int vcb[2] = { jperm(j0), 64 + jperm(j0) };
    const float* kbase = kp + (size_t)bh * Lq * Dd;
    const float* vbase = vp + (size_t)bh * Lq * Dd;

    // ---- prefetch iteration 0 ----
    float4 kr[2][4], vr[2][4];
    #pragma unroll
    for (int s = 0; s < 2; ++s)
        #pragma unroll
        for (int u = 0; u < 4; ++u) {
            kr[s][u] = *(const float4*)(kbase + (size_t)(64 * s + j0 + u) * Dd + c4);
            vr[s][u] = *(const float4*)(vbase + (size_t)(64 * s + j0 + u) * Dd + c4);
        }

    __syncthreads();                      // bias copy0 visible

    // ---- replicate bias copies 1..3 (copyP[i] = bias(i+P)) ----
    #pragma unroll
    for (int it = 0; it < 5; ++it) {
        int i = it * 256 + t;
        if (i < TB) {
            float b1 = bias4[i + 1 <= TB - 2 ? i + 1 : TB - 2];
            float b2 = bias4[i + 2 <= TB - 2 ? i + 2 : TB - 2];
            float b3 = bias4[i + 3 <= TB - 2 ? i + 3 : TB - 2];
            bias4[TB + i]     = b1;
            bias4[2 * TB + i] = b2;
            bias4[3 * TB + i] = b3;
        }
    }
    // ---- write tile 0: K row-major; V reg-transposed 4x4; packed converts --
    #pragma unroll
    for (int s = 0; s < 2; ++s) {
        #pragma unroll
        for (int u = 0; u < 4; ++u) {
            uint2 kv;
            kv.x = pk2(kr[s][u].x, kr[s][u].y);
            kv.y = pk2(kr[s][u].z, kr[s][u].w);
            *(uint2*)&k_s[(64 * s + j0 + u) * SRk + c4] = kv;
        }
        #pragma unroll
        for (int cc = 0; cc < 4; ++cc) {
            int d = c4 + cc;
            uint2 vv;
            vv.x = pk2(((const float*)&vr[s][0])[cc], ((const float*)&vr[s][1])[cc]);
            vv.y = pk2(((const float*)&vr[s][2])[cc], ((const float*)&vr[s][3])[cc]);
            *(uint2*)&v_s[d * SRv + (vcb[s] ^ (8 * ((d >> 3) & 7)))] = vv;
        }
    }
    __syncthreads();

    // ---- accumulators ----
    f32x16 O0, O1;
    #pragma unroll
    for (int r = 0; r < 16; ++r) { O0[r] = 0.f; O1[r] = 0.f; }
    float l_part = 0.0f;

    const int L0 = 4 * h5 - 32 * w - l31 + 127;   // bias lane offset
    const int phi = L0 & 3;
    const float* bcopy = bias4 + phi * TB - phi;  // aligned-float4 view

    #pragma unroll 1
    for (int kt = 0; kt < Lq / KT; ++kt) {        // 8 iterations
        const int ks = kt * KT;

        // prefetch next iteration (VMEM overlaps compute below)
        if (kt < 7) {
            const float* kn = kbase + (size_t)(ks + KT) * Dd;
            const float* vn = vbase + (size_t)(ks + KT) * Dd;
            #pragma unroll
            for (int s = 0; s < 2; ++s)
                #pragma unroll
                for (int u = 0; u < 4; ++u) {
                    kr[s][u] = *(const float4*)(kn + (size_t)(64 * s + j0 + u) * Dd + c4);
                    vr[s][u] = *(const float4*)(vn + (size_t)(64 * s + j0 + u) * Dd + c4);
                }
        }

        #pragma unroll
        for (int s = 0; s < 2; ++s) {
            // ---- S^T = K Q^T (sub-tile s) ----
            f32x16 S0, S1;
            #pragma unroll
            for (int r = 0; r < 16; ++r) { S0[r] = 0.f; S1[r] = 0.f; }
            #pragma unroll
            for (int c = 0; c < 4; ++c) {
                short8 ak0 = *(const short8*)&k_s[(64 * s + l31) * SRk + c * 16 + h5 * 8];
                S0 = __builtin_amdgcn_mfma_f32_32x32x16_bf16(ak0, bq[c], S0, 0, 0, 0);
            }
            #pragma unroll
            for (int c = 0; c < 4; ++c) {
                short8 ak1 = *(const short8*)&k_s[(64 * s + 32 + l31) * SRk + c * 16 + h5 * 8];
                S1 = __builtin_amdgcn_mfma_f32_32x32x16_bf16(ak1, bq[c], S1, 0, 0, 0);
            }

            // ---- softmax: p = exp2(S + bias') ----
            float lsum = 0.0f;
            #pragma unroll
            for (int p = 0; p < 4; ++p) {
                int base0 = ks + 64 * s + 8 * p + L0;
                float4 b0 = *(const float4*)(bcopy + base0);
                float4 b1 = *(const float4*)(bcopy + base0 + 32);
                #pragma unroll
                for (int q = 0; q < 4; ++q) {
                    int r = 4 * p + q;
                    float bq0 = (q == 0) ? b0.x : (q == 1) ? b0.y : (q == 2) ? b0.z : b0.w;
                    float bq1 = (q == 0) ? b1.x : (q == 1) ? b1.y : (q == 2) ? b1.z : b1.w;
                    float e0 = __builtin_amdgcn_exp2f(S0[r] + bq0);
                    float e1 = __builtin_amdgcn_exp2f(S1[r] + bq1);
                    S0[r] = e0; S1[r] = e1;
                    lsum += e0 + e1;
                }
            }
            l_part += lsum;

            // ---- P A-frags in-register (jperm trick), packed converts:
            // frag pairs (e,e+1) map to consecutive S regs -> one pk2 each
            short8 ap[4];
            #pragma unroll
            for (int c = 0; c < 4; ++c) {
                int b = (c & 1) * 4;
                u32x4 a;
                if (c >> 1) {
                    a[0] = pk2(S1[b + 0], S1[b + 1]);
                    a[1] = pk2(S1[b + 2], S1[b + 3]);
                    a[2] = pk2(S1[b + 8], S1[b + 9]);
                    a[3] = pk2(S1[b + 10], S1[b + 11]);
                } else {
                    a[0] = pk2(S0[b + 0], S0[b + 1]);
                    a[1] = pk2(S0[b + 2], S0[b + 3]);
                    a[2] = pk2(S0[b + 8], S0[b + 9]);
                    a[3] = pk2(S0[b + 10], S0[b + 11]);
                }
                ap[c] = __builtin_bit_cast(short8, a);
            }

            // ---- O += P V (sub-tile s) ----
            #pragma unroll
            for (int nb = 0; nb < 2; ++nb) {
                int d = nb * 32 + l31;
                int swz = 8 * ((d >> 3) & 7);
                f32x16 acc = nb ? O1 : O0;
                #pragma unroll
                for (int c = 0; c < 4; ++c) {
                    short8 bv = *(const short8*)&v_s[d * SRv + 64 * s + ((c * 16 + h5 * 8) ^ swz)];
                    acc = __builtin_amdgcn_mfma_f32_32x32x16_bf16(ap[c], bv, acc, 0, 0, 0);
                }
                if (nb) O1 = acc; else O0 = acc;
            }
        }

        __syncthreads();                  // all waves done reading k_s/v_s
        if (kt < 7) {
            #pragma unroll
            for (int s = 0; s < 2; ++s) {
                #pragma unroll
                for (int u = 0; u < 4; ++u) {
                    uint2 kv;
                    kv.x = pk2(kr[s][u].x, kr[s][u].y);
                    kv.y = pk2(kr[s][u].z, kr[s][u].w);
                    *(uint2*)&k_s[(64 * s + j0 + u) * SRk + c4] = kv;
                }
                #pragma unroll
                for (int cc = 0; cc < 4; ++cc) {
                    int d = c4 + cc;
                    uint2 vv;
                    vv.x = pk2(((const float*)&vr[s][0])[cc], ((const float*)&vr[s][1])[cc]);
                    vv.y = pk2(((const float*)&vr[s][2])[cc], ((const float*)&vr[s][3])[cc]);
                    *(uint2*)&v_s[d * SRv + (vcb[s] ^ (8 * ((d >> 3) & 7)))] = vv;
                }
            }
        }
        __syncthreads();
    }

    // ---- epilogue: finish row sums (i = l31), normalize, store ----
    float l = l_part;
    l += __shfl_xor(l, 32);               // other j-half
    l_s[32 * w + l31] = 1.0f / l;
    float* ob = out + ((size_t)bh * Lq + qs) * Dd;
    #pragma unroll
    for (int r = 0; r < 16; ++r) {
        int rowp = (r & 3) + 8 * (r >> 2) + 4 * h5;
        float inv = l_s[32 * w + rowp];   // same-wave write, wave-ordered
        ob[(size_t)(32 * w + rowp) * Dd + l31]      = O0[r] * inv;
        ob[(size_t)(32 * w + rowp) * Dd + 32 + l31] = O1[r] * inv;
    }
}

extern "C" void kernel_launch(void* const* d_in, const int* in_sizes, int n_in,
                              void* d_out, int out_size, void* d_ws, size_t ws_size,
                              hipStream_t stream) {
    const float* q   = (const float*)d_in[0];
    const float* k   = (const float*)d_in[1];
    const float* v   = (const float*)d_in[2];
    const float* off = (const float*)d_in[3];
    const float* amp = (const float*)d_in[4];
    const float* sh  = (const float*)d_in[5];
    const float* bp  = (const float*)d_in[6];
    float* out = (float*)d_out;

    dim3 grid(Bq * Hh, Lq / QT);          // (64, 8), bh fastest -> XCD locality
    attn_kernel<<<grid, 256, 0, stream>>>(q, k, v, off, amp, sh, bp, out);
}